// Round 5
// baseline (1424.493 us; speedup 1.0000x reference)
//
#include <hip/hip_runtime.h>

static constexpr int TT = 512;   // sequence length
static constexpr int BB = 256;   // batch

// LDS-only barrier: no vmcnt(0) drain, so global loads/stores stay in flight
// across it (T4/T14 pattern). lgkmcnt(0) makes prior LDS writes visible.
#define BARRIER() do { \
    asm volatile("s_waitcnt lgkmcnt(0)" ::: "memory"); \
    __builtin_amdgcn_s_barrier(); \
    asm volatile("" ::: "memory"); \
  } while (0)

__device__ __forceinline__ float sigmoid_fast(float v) {
  const float e = __builtin_amdgcn_exp2f(v * -1.44269504088896340736f);
  return __builtin_amdgcn_rcpf(1.0f + e);
}
__device__ __forceinline__ float dpp_add_xor1(float v) {
  const int p = __builtin_amdgcn_update_dpp(0, __builtin_bit_cast(int, v),
                                            0xB1, 0xF, 0xF, true);
  return v + __builtin_bit_cast(float, p);
}
__device__ __forceinline__ float dpp_add_xor2(float v) {
  const int p = __builtin_amdgcn_update_dpp(0, __builtin_bit_cast(int, v),
                                            0x4E, 0xF, 0xF, true);
  return v + __builtin_bit_cast(float, p);
}
__device__ __forceinline__ float swz_add_xor4(float v) {
  const int p = __builtin_amdgcn_ds_swizzle(__builtin_bit_cast(int, v), 0x101F);
  return v + __builtin_bit_cast(float, p);
}

// ===================== pre-GEMM: C[M,512] = A[M,64] @ W[64,512] ============
// thread = one output column; W column in 64 regs reused over 128 rows;
// A-tile staged in LDS, rows read as wave-uniform broadcast float4s.
__global__ void __launch_bounds__(512, 2)
gemm_xk512(const float* __restrict__ A, const float* __restrict__ W,
           float* __restrict__ C)
{
  const int tid = (int)threadIdx.x;
  const int blk = (int)blockIdx.x;
  __shared__ __align__(16) float At[128 * 64];

  float w[64];
  #pragma unroll
  for (int k = 0; k < 64; ++k) w[k] = W[(size_t)k * 512 + tid];

  const size_t rbase = (size_t)blk * 128;
  #pragma unroll
  for (int i = 0; i < 4; ++i)
    ((float4*)At)[tid + 512 * i] = ((const float4*)(A + rbase * 64))[tid + 512 * i];
  __syncthreads();

  for (int r = 0; r < 128; ++r) {
    const float4* ar = (const float4*)(At + r * 64);
    float a0 = 0.f, a1 = 0.f, a2 = 0.f, a3 = 0.f;
    #pragma unroll
    for (int j = 0; j < 16; ++j) {
      const float4 v = ar[j];
      a0 = fmaf(v.x, w[4 * j + 0], a0);
      a1 = fmaf(v.y, w[4 * j + 1], a1);
      a2 = fmaf(v.z, w[4 * j + 2], a2);
      a3 = fmaf(v.w, w[4 * j + 3], a3);
    }
    C[(rbase + r) * 512 + tid] = (a0 + a1) + (a2 + a3);
  }
}

// ===================== H=128 recurrence, Wr-only (zx streamed) =============
// thread (u, sl): sl in [0,4) is both k-slice (32 of 128 h-k's) and gate
// carrier: lane sl initializes gate-sl's accumulator with zx[t][sl*H+u];
// the 2-level DPP butterfly then sums slices for every gate. w[128] regs.
template<bool WRITE_SEQ, bool FUSE_DENSE>
__global__ void __launch_bounds__(512, 2)
lstm_rec128(const float* __restrict__ zx,    // [B,T,512] = x@Wk (+impl. order i,f,g,o)
            const float* __restrict__ Wr,    // [128,512]
            const float* __restrict__ bias,  // [512]
            float* __restrict__ seq_out,     // [B,T,128] (WRITE_SEQ)
            const float* __restrict__ Wout,  // [128,64]  (FUSE_DENSE)
            const float* __restrict__ boutp, // [64]      (FUSE_DENSE)
            float* __restrict__ dense_out)   // [B,T,64]  (FUSE_DENSE)
{
  constexpr int H = 128, C4H = 512, NW = 8, DK = 16;
  const int tid = (int)threadIdx.x;
  const int b   = (int)blockIdx.x;
  const int l   = tid & 63;
  const int wv  = tid >> 6;
  const int sl  = l & 3;
  const int u   = wv * 16 + (l >> 2);

  __shared__ __align__(16) float hb[2][H];
  __shared__ __align__(16) float dp[2][FUSE_DENSE ? NW * 64 : 4];

  float w[128];                               // Wr slice: 32 k's x 4 gates
  #pragma unroll
  for (int i = 0; i < 32; ++i) {
    const float* col = &Wr[(size_t)(sl * 32 + i) * C4H];
    #pragma unroll
    for (int g = 0; g < 4; ++g) w[i * 4 + g] = col[g * H + u];
  }
  const float bi_ = bias[u], bf_ = bias[H + u], bg_ = bias[2 * H + u], bo_ = bias[3 * H + u];

  float wout_r[FUSE_DENSE ? DK : 1];
  float boutr = 0.f;
  if constexpr (FUSE_DENSE) {
    #pragma unroll
    for (int j = 0; j < DK; ++j) wout_r[j] = Wout[(size_t)(DK * wv + j) * 64 + l];
    boutr = boutp[l];
  }

  if (tid < H) hb[0][tid] = 0.f;
  const size_t zbase = (size_t)b * TT * C4H + (size_t)sl * H + u;
  float zq = zx[zbase];                       // zx row for t=0
  BARRIER();

  float cst = 0.f;
  constexpr int TEND = FUSE_DENSE ? TT + 2 : TT;

  for (int t = 0; t < TEND; ++t) {
    const int cur = t & 1, nxt = cur ^ 1;

    float zqn;                                // 1-step-ahead zx prefetch
    if (t + 1 < TT) zqn = zx[zbase + (size_t)(t + 1) * C4H];

    if (t < TT) {
      const float4* xv = (const float4*)&hb[cur][sl * 32];
      float ai = (sl == 0) ? zq : 0.f;
      float af = (sl == 1) ? zq : 0.f;
      float ag = (sl == 2) ? zq : 0.f;
      float ao = (sl == 3) ? zq : 0.f;
      #pragma unroll
      for (int j = 0; j < 8; ++j) {
        const float4 v = xv[j];
        const float* wj = &w[16 * j];
        ai = fmaf(v.x, wj[0],  ai);  af = fmaf(v.x, wj[1],  af);
        ag = fmaf(v.x, wj[2],  ag);  ao = fmaf(v.x, wj[3],  ao);
        ai = fmaf(v.y, wj[4],  ai);  af = fmaf(v.y, wj[5],  af);
        ag = fmaf(v.y, wj[6],  ag);  ao = fmaf(v.y, wj[7],  ao);
        ai = fmaf(v.z, wj[8],  ai);  af = fmaf(v.z, wj[9],  af);
        ag = fmaf(v.z, wj[10], ag);  ao = fmaf(v.z, wj[11], ao);
        ai = fmaf(v.w, wj[12], ai);  af = fmaf(v.w, wj[13], af);
        ag = fmaf(v.w, wj[14], ag);  ao = fmaf(v.w, wj[15], ao);
      }
      ai = dpp_add_xor1(ai); af = dpp_add_xor1(af);
      ag = dpp_add_xor1(ag); ao = dpp_add_xor1(ao);
      ai = dpp_add_xor2(ai); af = dpp_add_xor2(af);
      ag = dpp_add_xor2(ag); ao = dpp_add_xor2(ao);

      const float gi = sigmoid_fast(ai + bi_);
      const float gf = sigmoid_fast(af + bf_);
      const float go = sigmoid_fast(ao + bo_);
      const float gg = fmaxf(ag + bg_, 0.f);
      cst = fmaf(gf, cst, gi * gg);
      const float h = go * fmaxf(cst, 0.f);
      if (sl == 0) {
        hb[nxt][u] = h;
        if constexpr (WRITE_SEQ) seq_out[((size_t)b * TT + t) * H + u] = h;
      }
    }

    if constexpr (FUSE_DENSE) {               // r4-validated 2-stage dense pipe
      if (t >= 1 && t <= TT) {
        const float* hsrc = &hb[cur][DK * wv];
        float a = 0.f;
        #pragma unroll
        for (int j = 0; j < DK; j += 4) {
          const float4 hv = *(const float4*)(hsrc + j);
          a = fmaf(hv.x, wout_r[j + 0], a);
          a = fmaf(hv.y, wout_r[j + 1], a);
          a = fmaf(hv.z, wout_r[j + 2], a);
          a = fmaf(hv.w, wout_r[j + 3], a);
        }
        dp[(t - 1) & 1][wv * 64 + l] = a;
      }
      if (t >= 2 && wv == NW - 1) {
        const float* dq = dp[t & 1];
        float o = boutr;
        #pragma unroll
        for (int j = 0; j < NW; ++j) o += dq[j * 64 + l];
        dense_out[((size_t)b * TT + (t - 2)) * 64 + l] = o;
      }
    }

    if (t + 1 < TT) zq = zqn;
    if (t < TEND - 1) BARRIER();
  }
}

// ===================== dec1: const-z fold + producer-folded d1@Wd2k ========
// H=64, NSu=8. zin = z@Wd1k computed once into per-lane slice partials that
// re-enter the butterfly each step. Thread also owns Wd2k column tid (w2[64])
// and emits zx3[t-1] = h(t-1)@Wd2k from LDS-broadcast h. d1 never stored.
__global__ void __launch_bounds__(512, 2)
lstm_dec1_fold(const float* __restrict__ zrow, // [B,64]
               const float* __restrict__ Wk,   // [64,256]
               const float* __restrict__ Wr,   // [64,256]
               const float* __restrict__ bias, // [256]
               const float* __restrict__ W2,   // [64,512] (Wd2k)
               float* __restrict__ zx3)        // [B,T,512]
{
  constexpr int H = 64, C4H = 256;
  const int tid = (int)threadIdx.x;
  const int b   = (int)blockIdx.x;
  const int l   = tid & 63;
  const int wv  = tid >> 6;
  const int sl  = l & 7;
  const int u   = wv * 8 + (l >> 3);

  __shared__ __align__(16) float hb[2][H];
  __shared__ __align__(16) float zl[H];

  float w[32];                                // Wr slice: 8 k's x 4 gates
  #pragma unroll
  for (int i = 0; i < 8; ++i) {
    const float* col = &Wr[(size_t)(sl * 8 + i) * C4H];
    #pragma unroll
    for (int g = 0; g < 4; ++g) w[i * 4 + g] = col[g * H + u];
  }
  float w2[64];                               // Wd2k column tid
  #pragma unroll
  for (int k = 0; k < 64; ++k) w2[k] = W2[(size_t)k * 512 + tid];
  const float bi_ = bias[u], bf_ = bias[H + u], bg_ = bias[2 * H + u], bo_ = bias[3 * H + u];

  if (tid < 16) ((float4*)zl)[tid] = ((const float4*)(zrow + (size_t)b * H))[tid];
  if (tid < H) hb[0][tid] = 0.f;
  BARRIER();

  float zi = 0.f, zf = 0.f, zg = 0.f, zo = 0.f;   // z@Wd1k, once
  #pragma unroll
  for (int i = 0; i < 8; ++i) {
    const int k = sl * 8 + i;
    const float zv = zl[k];
    const float* col = &Wk[(size_t)k * C4H];
    zi = fmaf(zv, col[u],         zi);
    zf = fmaf(zv, col[H + u],     zf);
    zg = fmaf(zv, col[2 * H + u], zg);
    zo = fmaf(zv, col[3 * H + u], zo);
  }

  float cst = 0.f;
  for (int t = 0; t < TT + 1; ++t) {
    const int cur = t & 1, nxt = cur ^ 1;
    if (t < TT) {
      const float4* xv = (const float4*)&hb[cur][sl * 8];
      float ai = zi, af = zf, ag = zg, ao = zo;
      #pragma unroll
      for (int j = 0; j < 2; ++j) {
        const float4 v = xv[j];
        const float* wj = &w[16 * j];
        ai = fmaf(v.x, wj[0],  ai);  af = fmaf(v.x, wj[1],  af);
        ag = fmaf(v.x, wj[2],  ag);  ao = fmaf(v.x, wj[3],  ao);
        ai = fmaf(v.y, wj[4],  ai);  af = fmaf(v.y, wj[5],  af);
        ag = fmaf(v.y, wj[6],  ag);  ao = fmaf(v.y, wj[7],  ao);
        ai = fmaf(v.z, wj[8],  ai);  af = fmaf(v.z, wj[9],  af);
        ag = fmaf(v.z, wj[10], ag);  ao = fmaf(v.z, wj[11], ao);
        ai = fmaf(v.w, wj[12], ai);  af = fmaf(v.w, wj[13], af);
        ag = fmaf(v.w, wj[14], ag);  ao = fmaf(v.w, wj[15], ao);
      }
      ai = dpp_add_xor1(ai); af = dpp_add_xor1(af);
      ag = dpp_add_xor1(ag); ao = dpp_add_xor1(ao);
      ai = dpp_add_xor2(ai); af = dpp_add_xor2(af);
      ag = dpp_add_xor2(ag); ao = dpp_add_xor2(ao);
      ai = swz_add_xor4(ai); af = swz_add_xor4(af);
      ag = swz_add_xor4(ag); ao = swz_add_xor4(ao);

      const float gi = sigmoid_fast(ai + bi_);
      const float gf = sigmoid_fast(af + bf_);
      const float go = sigmoid_fast(ao + bo_);
      const float gg = fmaxf(ag + bg_, 0.f);
      cst = fmaf(gf, cst, gi * gg);
      const float h = go * fmaxf(cst, 0.f);
      if (sl == 0) hb[nxt][u] = h;
    }
    if (t >= 1) {                              // zx3[t-1] = h(t-1) @ Wd2k
      const float* hsrc = hb[cur];
      float a0 = 0.f, a1 = 0.f, a2 = 0.f, a3 = 0.f;
      #pragma unroll
      for (int k = 0; k < 64; k += 4) {
        const float4 hv = *(const float4*)(hsrc + k);
        a0 = fmaf(hv.x, w2[k + 0], a0);
        a1 = fmaf(hv.y, w2[k + 1], a1);
        a2 = fmaf(hv.z, w2[k + 2], a2);
        a3 = fmaf(hv.w, w2[k + 3], a3);
      }
      zx3[((size_t)b * TT + (t - 1)) * 512 + tid] = (a0 + a1) + (a2 + a3);
    }
    if (t < TT) BARRIER();
  }
}

// ===================== r4 proven template (enc2 + full fallback) ===========
template<int DIN, int H, int NSu, bool CONST_X, bool WRITE_SEQ, bool WRITE_LAST, bool FUSE_DENSE>
__global__ void __launch_bounds__(512, 2)
lstm_unit(const float* __restrict__ xin, const float* __restrict__ Wk,
          const float* __restrict__ Wr, const float* __restrict__ bias,
          float* __restrict__ seq_out, float* __restrict__ last_out,
          const float* __restrict__ Wout, const float* __restrict__ boutp,
          float* __restrict__ dense_out)
{
  constexpr int NTH  = 512;
  static_assert(H * NSu == NTH, "block = H*NSu = 512");
  constexpr int KTOT = DIN + H;
  constexpr int SL   = KTOT / NSu;
  constexpr int C4H  = 4 * H;
  constexpr int XH   = DIN + H;
  constexpr int NW   = NTH / 64;
  constexpr int UPW  = 64 / NSu;
  constexpr int DK   = FUSE_DENSE ? (H / NW) : 4;
  static_assert(SL * NSu == KTOT && (SL % 4) == 0, "slice float4-able");
  static_assert(NSu == 4 || NSu == 8, "butterfly depth");

  const int tid = (int)threadIdx.x;
  const int b   = (int)blockIdx.x;
  const int l   = tid & 63;
  const int wv  = tid >> 6;
  const int sl  = l & (NSu - 1);
  const int u   = wv * UPW + (l / NSu);

  __shared__ __align__(16) float xh0[XH], xh1[XH];
  __shared__ __align__(16) float dp[2][FUSE_DENSE ? NW * 64 : 4];

  float w[SL * 4];
  #pragma unroll
  for (int i = 0; i < SL; ++i) {
    const int k = sl * SL + i;
    const float* col = (k < DIN) ? &Wk[(size_t)k * C4H] : &Wr[(size_t)(k - DIN) * C4H];
    #pragma unroll
    for (int g = 0; g < 4; ++g) w[i * 4 + g] = col[g * H + u];
  }
  const float bi_ = bias[u], bf_ = bias[H + u], bg_ = bias[2 * H + u], bo_ = bias[3 * H + u];

  float wout_r[DK];
  float boutr = 0.f;
  if constexpr (FUSE_DENSE) {
    #pragma unroll
    for (int j = 0; j < DK; ++j) wout_r[j] = Wout[(size_t)(DK * wv + j) * 64 + l];
    boutr = boutp[l];
  }

  if (tid < H) xh0[DIN + tid] = 0.f;
  if (tid < DIN / 4) {
    const float4 v = *(const float4*)&xin[(CONST_X ? (size_t)b * DIN
                                                   : (size_t)b * TT * DIN) + 4 * tid];
    *((float4*)xh0 + tid) = v;
    if (CONST_X) *((float4*)xh1 + tid) = v;
  }
  BARRIER();

  float cst = 0.f;
  constexpr int TEND = FUSE_DENSE ? TT + 2 : TT;

  for (int t = 0; t < TEND; ++t) {
    float* xc = (t & 1) ? xh1 : xh0;
    float* xn = (t & 1) ? xh0 : xh1;

    float4 xr;
    const bool do_stage = (!CONST_X) && (tid < DIN / 4) && (t + 1 < TT);
    if (do_stage) xr = *(const float4*)&xin[((size_t)b * TT + (t + 1)) * DIN + 4 * tid];

    if (t < TT) {
      const float4* xv = (const float4*)(xc + sl * SL);
      float ai = 0.f, af = 0.f, ag = 0.f, ao = 0.f;
      #pragma unroll
      for (int j = 0; j < SL / 4; ++j) {
        const float4 v = xv[j];
        const float* wj = &w[16 * j];
        ai = fmaf(v.x, wj[0],  ai);  af = fmaf(v.x, wj[1],  af);
        ag = fmaf(v.x, wj[2],  ag);  ao = fmaf(v.x, wj[3],  ao);
        ai = fmaf(v.y, wj[4],  ai);  af = fmaf(v.y, wj[5],  af);
        ag = fmaf(v.y, wj[6],  ag);  ao = fmaf(v.y, wj[7],  ao);
        ai = fmaf(v.z, wj[8],  ai);  af = fmaf(v.z, wj[9],  af);
        ag = fmaf(v.z, wj[10], ag);  ao = fmaf(v.z, wj[11], ao);
        ai = fmaf(v.w, wj[12], ai);  af = fmaf(v.w, wj[13], af);
        ag = fmaf(v.w, wj[14], ag);  ao = fmaf(v.w, wj[15], ao);
      }
      ai = dpp_add_xor1(ai); af = dpp_add_xor1(af);
      ag = dpp_add_xor1(ag); ao = dpp_add_xor1(ao);
      ai = dpp_add_xor2(ai); af = dpp_add_xor2(af);
      ag = dpp_add_xor2(ag); ao = dpp_add_xor2(ao);
      if constexpr (NSu == 8) {
        ai = swz_add_xor4(ai); af = swz_add_xor4(af);
        ag = swz_add_xor4(ag); ao = swz_add_xor4(ao);
      }
      const float gi = sigmoid_fast(ai + bi_);
      const float gf = sigmoid_fast(af + bf_);
      const float go = sigmoid_fast(ao + bo_);
      const float gg = fmaxf(ag + bg_, 0.f);
      cst = fmaf(gf, cst, gi * gg);
      const float h = go * fmaxf(cst, 0.f);
      if (sl == 0) {
        xn[DIN + u] = h;
        if constexpr (WRITE_SEQ)  seq_out[((size_t)b * TT + t) * H + u] = h;
        if constexpr (WRITE_LAST) { if (t == TT - 1) last_out[(size_t)b * H + u] = h; }
      }
    }
    if (do_stage) *((float4*)xn + tid) = xr;

    if constexpr (FUSE_DENSE) {
      if (t >= 1 && t <= TT) {
        const float* hsrc = xc + DIN + DK * wv;
        float a = 0.f;
        #pragma unroll
        for (int j = 0; j < DK; j += 4) {
          const float4 hv = *(const float4*)(hsrc + j);
          a = fmaf(hv.x, wout_r[j + 0], a);
          a = fmaf(hv.y, wout_r[j + 1], a);
          a = fmaf(hv.z, wout_r[j + 2], a);
          a = fmaf(hv.w, wout_r[j + 3], a);
        }
        dp[(t - 1) & 1][wv * 64 + l] = a;
      }
      if (t >= 2 && wv == NW - 1) {
        const float* dq = dp[t & 1];
        float o = boutr;
        #pragma unroll
        for (int j = 0; j < NW; ++j) o += dq[j * 64 + l];
        dense_out[((size_t)b * TT + (t - 2)) * 64 + l] = o;
      }
    }
    if (t < TEND - 1) BARRIER();
  }
}

extern "C" void kernel_launch(void* const* d_in, const int* in_sizes, int n_in,
                              void* d_out, int out_size, void* d_ws, size_t ws_size,
                              hipStream_t stream) {
  const float* x    = (const float*)d_in[0];
  const float* Wk1  = (const float*)d_in[1];
  const float* Wr1  = (const float*)d_in[2];
  const float* b1   = (const float*)d_in[3];
  const float* Wk2  = (const float*)d_in[4];
  const float* Wr2  = (const float*)d_in[5];
  const float* b2   = (const float*)d_in[6];
  const float* Wd1k = (const float*)d_in[7];
  const float* Wd1r = (const float*)d_in[8];
  const float* bd1  = (const float*)d_in[9];
  const float* Wd2k = (const float*)d_in[10];
  const float* Wd2r = (const float*)d_in[11];
  const float* bd2  = (const float*)d_in[12];
  const float* Wout = (const float*)d_in[13];
  const float* bout = (const float*)d_in[14];
  float* out = (float*)d_out;

  const size_t BT       = (size_t)BB * TT;            // 131072 rows
  const size_t zx_elems = BT * 512;                   // 256 MB region (zx1/zx3)
  const size_t h1_elems = BT * 128;                   // 64 MB
  const size_t need_big   = (zx_elems + h1_elems + (size_t)BB * 64) * sizeof(float);
  const size_t need_small = (h1_elems + (size_t)BB * 64) * sizeof(float);

  if (ws_size >= need_big) {
    float* zxA = (float*)d_ws;                        // zx1, later zx3
    float* h1  = zxA + zx_elems;
    float* z   = h1 + h1_elems;

    // 1) zx1 = x @ Wk1                       [B,T,512]
    gemm_xk512<<<(int)(BT / 128), 512, 0, stream>>>(x, Wk1, zxA);
    // 2) encoder 1 recurrence (Wr1 only) -> h1 [B,T,128]
    lstm_rec128<true, false><<<BB, 512, 0, stream>>>(
        zxA, Wr1, b1, h1, nullptr, nullptr, nullptr);
    // 3) encoder 2 (r4 form): h1 -> z [B,64]
    lstm_unit<128, 64, 8, false, false, true, false><<<BB, 512, 0, stream>>>(
        h1, Wk2, Wr2, b2, nullptr, z, nullptr, nullptr, nullptr);
    // 4) decoder 1 with const-z fold; emits zx3 = d1 @ Wd2k directly
    lstm_dec1_fold<<<BB, 512, 0, stream>>>(z, Wd1k, Wd1r, bd1, Wd2k, zxA);
    // 5) decoder 2 recurrence (Wd2r only) + fused TimeDistributed Dense
    lstm_rec128<false, true><<<BB, 512, 0, stream>>>(
        zxA, Wd2r, bd2, nullptr, Wout, bout, out);
  } else if (ws_size >= need_small) {
    // fallback: r4 pipeline (1422 us), no large-ws requirement
    float* h1 = (float*)d_ws;
    float* z  = h1 + h1_elems;
    float* d1 = h1;
    lstm_unit<64, 128, 4, false, true,  false, false><<<BB, 512, 0, stream>>>(
        x,  Wk1,  Wr1,  b1,  h1,      nullptr, nullptr, nullptr, nullptr);
    lstm_unit<128, 64, 8, false, false, true,  false><<<BB, 512, 0, stream>>>(
        h1, Wk2,  Wr2,  b2,  nullptr, z,       nullptr, nullptr, nullptr);
    lstm_unit<64,  64, 8, true,  true,  false, false><<<BB, 512, 0, stream>>>(
        z,  Wd1k, Wd1r, bd1, d1,      nullptr, nullptr, nullptr, nullptr);
    lstm_unit<64, 128, 4, false, false, false, true ><<<BB, 512, 0, stream>>>(
        d1, Wd2k, Wd2r, bd2, nullptr, nullptr, Wout,   bout,    out);
  }
}